// Round 4
// baseline (465.260 us; speedup 1.0000x reference)
//
#include <hip/hip_runtime.h>
#include <math.h>

#define N_NODES   100000
#define N_EDGES   1600000
#define NODE_F    128
#define EDGE_F    128
#define GLOB_F    64
#define N_GRAPHS  256
#define HIDDEN    128
#define IN_DIM    320   // 128 + 128 + 64

#define SCAN_CHUNK 2048
#define NSCAN ((N_NODES + SCAN_CHUNK - 1) / SCAN_CHUNK)   // 49

typedef __bf16 bf16x8 __attribute__((ext_vector_type(8)));
typedef __bf16 bf16x4 __attribute__((ext_vector_type(4)));
typedef float  f32x4  __attribute__((ext_vector_type(4)));

__device__ __forceinline__ void cvt_store4(__bf16* p, float x, float y, float z, float w) {
    bf16x4 b = { (__bf16)x, (__bf16)y, (__bf16)z, (__bf16)w };
    *reinterpret_cast<bf16x4*>(p) = b;
}

// ---------------------------------------------------------------------------
// W (f32 [128,320]) -> bf16, once.
// ---------------------------------------------------------------------------
__global__ __launch_bounds__(256) void wbf_kernel(const float* __restrict__ W,
                                                  __bf16* __restrict__ wbf) {
    int i = blockIdx.x * 256 + threadIdx.x;   // 160 blocks x 256 = 40960 exact
    wbf[i] = (__bf16)W[i];
}

// ---------------------------------------------------------------------------
// CSR build: histogram(+rank) -> scan -> fill (atomic-free)
// ---------------------------------------------------------------------------
__global__ __launch_bounds__(256) void hist_kernel(const int* __restrict__ dst,
                                                   int* __restrict__ counts,
                                                   int* __restrict__ rank) {
    int i = blockIdx.x * 256 + threadIdx.x;   // 6250 x 256 = 1.6M exact
    if (i < N_EDGES) rank[i] = atomicAdd(&counts[dst[i]], 1);
}

__global__ __launch_bounds__(256) void scan1_kernel(const int* __restrict__ counts,
                                                    int* __restrict__ partial) {
    __shared__ int red[256];
    int tid = threadIdx.x;
    int base = blockIdx.x * SCAN_CHUNK + tid * 8;
    int s = 0;
    #pragma unroll
    for (int j = 0; j < 8; ++j) {
        int idx = base + j;
        if (idx < N_NODES) s += counts[idx];
    }
    red[tid] = s;
    __syncthreads();
    for (int off = 128; off > 0; off >>= 1) {
        if (tid < off) red[tid] += red[tid + off];
        __syncthreads();
    }
    if (tid == 0) partial[blockIdx.x] = red[0];
}

__global__ __launch_bounds__(64) void scan2_kernel(const int* __restrict__ partial,
                                                   int* __restrict__ pscan) {
    if (threadIdx.x == 0) {
        int run = 0;
        for (int b = 0; b < NSCAN; ++b) { pscan[b] = run; run += partial[b]; }
    }
}

__global__ __launch_bounds__(256) void scan3_kernel(const int* __restrict__ counts,
                                                    const int* __restrict__ pscan,
                                                    int* __restrict__ offs) {
    __shared__ int ts[256];
    int tid = threadIdx.x;
    int base = blockIdx.x * SCAN_CHUNK + tid * 8;
    int c[8];
    int tot = 0;
    #pragma unroll
    for (int j = 0; j < 8; ++j) {
        int idx = base + j;
        c[j] = (idx < N_NODES) ? counts[idx] : 0;
        tot += c[j];
    }
    ts[tid] = tot;
    __syncthreads();
    for (int off = 1; off < 256; off <<= 1) {
        int v = 0;
        if (tid >= off) v = ts[tid - off];
        __syncthreads();
        if (tid >= off) ts[tid] += v;
        __syncthreads();
    }
    int run = pscan[blockIdx.x] + ts[tid] - tot;   // exclusive prefix
    #pragma unroll
    for (int j = 0; j < 8; ++j) {
        int idx = base + j;
        if (idx < N_NODES) { offs[idx] = run; run += c[j]; }
    }
    if (blockIdx.x == 0 && tid == 0) offs[N_NODES] = N_EDGES;
}

__global__ __launch_bounds__(256) void fill_kernel(const int* __restrict__ dst,
                                                   const int* __restrict__ rank,
                                                   const int* __restrict__ offs,
                                                   int* __restrict__ eid) {
    int i = blockIdx.x * 256 + threadIdx.x;
    if (i < N_EDGES) {
        int d = dst[i];
        eid[offs[d] + rank[i]] = i;
    }
}

// ---------------------------------------------------------------------------
// Fused: CSR gather-mean + concat (into LDS as bf16) + MFMA GEMM + softplus.
// Block = 256 threads (4 waves), 32 rows x 128 cols of output.
// Gather: wave = 4 x 16-lane groups; each group processes its TWO rows in one
// joint, branch-free loop (indices clamped, contributions fmaf-masked) ->
// 64 independent 16B edge loads in flight per group. offs + first eid batch
// prefetched above the node/glob staging. Edge loads are non-temporal so the
// L2-resident bf16 W copy survives the 819MB stream.
// GEMM: A from LDS, B (W) read directly from global bf16 copy; barrier-free.
// ---------------------------------------------------------------------------
#define ROWS 32
#define XSTR (IN_DIM + 8)     // 328 bf16 -> 656 B row stride (16B-aligned)

__global__ __launch_bounds__(256) void fused_kernel(
    const float* __restrict__ node_feats,   // [N_NODES,128]
    const float* __restrict__ edge_feats,   // [N_EDGES,128]
    const float* __restrict__ glob,         // [256,64]
    const int*   __restrict__ batch,        // [N_NODES]
    const __bf16* __restrict__ wbf,         // [128,320] bf16
    const int*   __restrict__ offs,         // [N_NODES+1]
    const int*   __restrict__ eid,          // [N_EDGES]
    float* __restrict__ out)                // [N_NODES,128]
{
    __shared__ __bf16 xs[ROWS * XSTR];      // 20992 B (only LDS use)

    const int tid  = threadIdx.x;
    const int row0 = blockIdx.x * ROWS;
    const int wv   = tid >> 6;
    const int lane = tid & 63;
    const int gl   = lane & 15;             // lane within 16-group
    const int grp  = lane >> 4;             // group 0..3

    // ---- this group's two rows; issue offs + first eid loads FIRST
    const int r0 = wv * 8 + grp;
    const int r1 = r0 + 4;
    const int beg0 = offs[row0 + r0], end0 = offs[row0 + r0 + 1];
    const int beg1 = offs[row0 + r1], end1 = offs[row0 + r1 + 1];
    const int E0 = end0 - beg0, E1 = end1 - beg1;
    const int lim0 = max(end0 - 1, 0);
    const int lim1 = max(end1 - 1, 0);
    int ev0 = eid[min(beg0 + gl, lim0)];
    int ev1 = eid[min(beg1 + gl, lim1)];

    // ---- stage node features -> xs[:, 0:128)
    #pragma unroll
    for (int it = 0; it < 4; ++it) {
        int i = tid + it * 256;             // 0..1023
        int r = i >> 5, k4 = i & 31;
        float4 v = *reinterpret_cast<const float4*>(
            node_feats + (size_t)(row0 + r) * NODE_F + k4 * 4);
        cvt_store4(&xs[r * XSTR + k4 * 4], v.x, v.y, v.z, v.w);
    }
    // ---- stage globals -> xs[:, 256:320)
    #pragma unroll
    for (int it = 0; it < 2; ++it) {
        int i = tid + it * 256;             // 0..511
        int r = i >> 4, k4 = i & 15;
        int b = batch[row0 + r];
        float4 v = *reinterpret_cast<const float4*>(
            glob + (size_t)b * GLOB_F + k4 * 4);
        cvt_store4(&xs[r * XSTR + NODE_F + EDGE_F + k4 * 4], v.x, v.y, v.z, v.w);
    }

    // ---- joint branch-free gather for both rows
    float s00=0.f,s01=0.f,s02=0.f,s03=0.f,s04=0.f,s05=0.f,s06=0.f,s07=0.f;
    float s10=0.f,s11=0.f,s12=0.f,s13=0.f,s14=0.f,s15=0.f,s16=0.f,s17=0.f;
    const int Emax = max(E0, E1);
    for (int c0 = 0; c0 < Emax; c0 += 16) {
        #pragma unroll
        for (int i = 0; i < 16; ++i) {
            int e0 = __shfl(ev0, (lane & 48) + i);
            int e1 = __shfl(ev1, (lane & 48) + i);
            const f32x4* p0 = reinterpret_cast<const f32x4*>(
                edge_feats + (size_t)e0 * EDGE_F + gl * 8);
            const f32x4* p1 = reinterpret_cast<const f32x4*>(
                edge_feats + (size_t)e1 * EDGE_F + gl * 8);
            f32x4 u0 = __builtin_nontemporal_load(p0);
            f32x4 u1 = __builtin_nontemporal_load(p0 + 1);
            f32x4 w0 = __builtin_nontemporal_load(p1);
            f32x4 w1 = __builtin_nontemporal_load(p1 + 1);
            float m0 = (c0 + i < E0) ? 1.f : 0.f;
            float m1 = (c0 + i < E1) ? 1.f : 0.f;
            s00 = fmaf(u0.x, m0, s00); s01 = fmaf(u0.y, m0, s01);
            s02 = fmaf(u0.z, m0, s02); s03 = fmaf(u0.w, m0, s03);
            s04 = fmaf(u1.x, m0, s04); s05 = fmaf(u1.y, m0, s05);
            s06 = fmaf(u1.z, m0, s06); s07 = fmaf(u1.w, m0, s07);
            s10 = fmaf(w0.x, m1, s10); s11 = fmaf(w0.y, m1, s11);
            s12 = fmaf(w0.z, m1, s12); s13 = fmaf(w0.w, m1, s13);
            s14 = fmaf(w1.x, m1, s14); s15 = fmaf(w1.y, m1, s15);
            s16 = fmaf(w1.z, m1, s16); s17 = fmaf(w1.w, m1, s17);
        }
        ev0 = eid[min(beg0 + c0 + 16 + gl, lim0)];
        ev1 = eid[min(beg1 + c0 + 16 + gl, lim1)];
    }
    {
        float ic0 = 1.0f / fmaxf((float)E0, 1.0f);
        float ic1 = 1.0f / fmaxf((float)E1, 1.0f);
        bf16x8 b0, b1;
        b0[0]=(__bf16)(s00*ic0); b0[1]=(__bf16)(s01*ic0);
        b0[2]=(__bf16)(s02*ic0); b0[3]=(__bf16)(s03*ic0);
        b0[4]=(__bf16)(s04*ic0); b0[5]=(__bf16)(s05*ic0);
        b0[6]=(__bf16)(s06*ic0); b0[7]=(__bf16)(s07*ic0);
        b1[0]=(__bf16)(s10*ic1); b1[1]=(__bf16)(s11*ic1);
        b1[2]=(__bf16)(s12*ic1); b1[3]=(__bf16)(s13*ic1);
        b1[4]=(__bf16)(s14*ic1); b1[5]=(__bf16)(s15*ic1);
        b1[6]=(__bf16)(s16*ic1); b1[7]=(__bf16)(s17*ic1);
        *reinterpret_cast<bf16x8*>(&xs[r0 * XSTR + NODE_F + gl * 8]) = b0;
        *reinterpret_cast<bf16x8*>(&xs[r1 * XSTR + NODE_F + gl * 8]) = b1;
    }

    __syncthreads();   // xs complete; k-loop below is barrier-free

    f32x4 acc00 = {0.f, 0.f, 0.f, 0.f};
    f32x4 acc10 = {0.f, 0.f, 0.f, 0.f};
    f32x4 acc01 = {0.f, 0.f, 0.f, 0.f};
    f32x4 acc11 = {0.f, 0.f, 0.f, 0.f};

    const int lr = lane & 15;    // row/col within MFMA tile
    const int kb = lane >> 4;    // k-block of 8

    const __bf16* wrow0 = wbf + (size_t)(wv * 32 + lr) * IN_DIM + kb * 8;
    const __bf16* wrow1 = wrow0 + 16 * IN_DIM;

    #pragma unroll 2
    for (int kt = 0; kt < IN_DIM / 32; ++kt) {     // 10 k-steps
        bf16x8 a0 = *reinterpret_cast<const bf16x8*>(&xs[lr * XSTR + kt * 32 + kb * 8]);
        bf16x8 a1 = *reinterpret_cast<const bf16x8*>(&xs[(16 + lr) * XSTR + kt * 32 + kb * 8]);
        bf16x8 b0 = *reinterpret_cast<const bf16x8*>(wrow0 + kt * 32);
        bf16x8 b1 = *reinterpret_cast<const bf16x8*>(wrow1 + kt * 32);

        acc00 = __builtin_amdgcn_mfma_f32_16x16x32_bf16(a0, b0, acc00, 0, 0, 0);
        acc10 = __builtin_amdgcn_mfma_f32_16x16x32_bf16(a1, b0, acc10, 0, 0, 0);
        acc01 = __builtin_amdgcn_mfma_f32_16x16x32_bf16(a0, b1, acc01, 0, 0, 0);
        acc11 = __builtin_amdgcn_mfma_f32_16x16x32_bf16(a1, b1, acc11, 0, 0, 0);
    }

    // ---- epilogue: shifted softplus, C/D layout col=lane&15, row=(lane>>4)*4+q
    const float LN2 = 0.69314718055994530942f;
#define EMIT(ACC, RT, CT)                                                      \
    do {                                                                       \
        int col = (wv * 2 + (CT)) * 16 + lr;                                   \
        _Pragma("unroll")                                                      \
        for (int q = 0; q < 4; ++q) {                                          \
            int row = row0 + (RT) * 16 + kb * 4 + q;                           \
            float h = ACC[q];                                                  \
            float sp = fmaxf(h, 0.f) + log1pf(__expf(-fabsf(h)));              \
            out[(size_t)row * HIDDEN + col] = sp - LN2;                        \
        }                                                                      \
    } while (0)
    EMIT(acc00, 0, 0);
    EMIT(acc10, 1, 0);
    EMIT(acc01, 0, 1);
    EMIT(acc11, 1, 1);
#undef EMIT
}

// ---------------------------------------------------------------------------
extern "C" void kernel_launch(void* const* d_in, const int* in_sizes, int n_in,
                              void* d_out, int out_size, void* d_ws, size_t ws_size,
                              hipStream_t stream) {
    const float* node_feats = (const float*)d_in[0];   // [100000,128]
    const float* edge_feats = (const float*)d_in[1];   // [1600000,128]
    const float* glob       = (const float*)d_in[2];   // [256,64]
    const float* W          = (const float*)d_in[3];   // [128,320]
    const int*   edge_index = (const int*)d_in[4];     // [2,1600000]
    const int*   batch      = (const int*)d_in[5];     // [100000]
    float* out = (float*)d_out;                        // [100000,128]

    const int* dst = edge_index + N_EDGES;             // row 1 = destinations

    // workspace layout
    __bf16* wbf = (__bf16*)d_ws;                       // 40960 bf16 = 81920 B
    int* ws_i   = (int*)((char*)d_ws + 81920);
    int* counts  = ws_i;                               // 100000
    int* partial = ws_i + 100000;                      // 64
    int* pscan   = ws_i + 100064;                      // 64
    int* offs    = ws_i + 100128;                      // 100001
    int* eid     = ws_i + 200132;                      // 1600000
    int* rank    = ws_i + 1800132;                     // 1600000  (ends ~13.7 MB)

    hipMemsetAsync(counts, 0, (size_t)N_NODES * sizeof(int), stream);

    wbf_kernel<<<160, 256, 0, stream>>>(W, wbf);
    hist_kernel<<<N_EDGES / 256, 256, 0, stream>>>(dst, counts, rank);
    scan1_kernel<<<NSCAN, 256, 0, stream>>>(counts, partial);
    scan2_kernel<<<1, 64, 0, stream>>>(partial, pscan);
    scan3_kernel<<<NSCAN, 256, 0, stream>>>(counts, pscan, offs);
    fill_kernel<<<N_EDGES / 256, 256, 0, stream>>>(dst, rank, offs, eid);

    fused_kernel<<<N_NODES / ROWS, 256, 0, stream>>>(
        node_feats, edge_feats, glob, batch, wbf, offs, eid, out);
}